// Round 14
// baseline (75.143 us; speedup 1.0000x reference)
//
#include <hip/hip_runtime.h>

// ACT-R activation recurrence — async spine + register-decoupled serial chain.
// s_i = sum_{j<i} ((t_i-t_j)*H)^(-decay_j),  decay_j = w0 + w1*s_j  (s_0=0)
// (reference's max(diff*H,1) never binds: min gap 0.05 days * 2160 = 108)
// out[i-1,b] = sigmoid((ln(s_i)-TAU)/S), i=1..L-1.
//
// Identity: diff^(-decay_j) = exp2(q_ij*alpha_j), q_ij = -w1*log2(diff_ij),
// alpha = s + w0/w1 > 0; masked q = -1e30 -> term 0.
//
// R14 chain fix: in R9-R13 the readlane broadcast source and the band
// accumulator were the SAME register, written every step by a full-wave op;
// per-REGISTER dependency tracking serialized every rdlane behind the whole
// previous vector update (~90 cyc/link). Now:
//  - vector q-table masks j <= l-3; the two subdiagonals go scalar-side
//    (qd1: j=l-1 on the serial path; qd2: j=l-2 exp2'd one step EARLY).
//  - band split into bE/bO (alternating cols): every rdlane reads a register
//    last written >= 1 full step ago, and prefetches precede the band write
//    (value-safe by mask) -> serial path = mul->exp2->add.
// Everything else identical to R13's barrier-free producer/consumer spine.

constexpr int   L  = 1024;
constexpr int   B  = 256;
constexpr int   T  = 64;
constexpr int   NT = 512;    // 8 waves: 1 chain + 7 workers

constexpr float H_CONST = 86400.0f * 0.025f;   // 2160
constexpr float TAU_C   = -0.704205679427144f;
constexpr float S_C     = 0.254893976981164f;
constexpr float LN2     = 0.69314718055994530942f;
constexpr float LOG2E   = 1.4426950408889634074f;
constexpr float BIGNEG  = -1e30f;

// cos(k*pi/16)
constexpr float CC1 = 0.98078528040323044913f;
constexpr float CC2 = 0.92387953251128675613f;
constexpr float CC3 = 0.83146961230254523708f;
constexpr float CC4 = 0.70710678118654752440f;
constexpr float CC5 = 0.55557023301960222474f;
constexpr float CC6 = 0.38268343236508977173f;
constexpr float CC7 = 0.19509032201612826785f;

__device__ static const float UNODE[8] =
  { CC1, CC3, CC5, CC7, -CC7, -CC5, -CC3, -CC1 };

typedef float f32x4 __attribute__((ext_vector_type(4)));

__device__ __forceinline__ float flog2(float x) { return __builtin_amdgcn_logf(x); }
__device__ __forceinline__ float fexp2(float x) { return __builtin_amdgcn_exp2f(x); }
__device__ __forceinline__ float rdlane(float v, int l) {
    return __uint_as_float(__builtin_amdgcn_readlane(__float_as_uint(v), l));
}

#define LOADCH(p0, p1, p2, p3, c)                                   \
    p0 = *(const f32x4*)(qb + 4 * ((4 * (c) + 0) ^ xk));            \
    p1 = *(const f32x4*)(qb + 4 * ((4 * (c) + 1) ^ xk));            \
    p2 = *(const f32x4*)(qb + 4 * ((4 * (c) + 2) ^ xk));            \
    p3 = *(const f32x4*)(qb + 4 * ((4 * (c) + 3) ^ xk));

#define KEEP4(a, b, c, d) \
    asm volatile("" : "+v"(a), "+v"(b), "+v"(c), "+v"(d));

// band register for the col applied at step J (col J-1)
#define BAND(J) (((J) & 1) ? bE : bO)

// step J (1..63): produces sig_J. Entering: sig1 = sig_{J-1},
// sPP = alpha0_J + band_J + exp2(qd2_J*sig_{J-2}), sQ1 = qd1_J, sQ2n = qd2_{J+1}.
// Prefetches (top) read registers last written a full step ago -> no hazard.
#define CSTEP(QE, J) {                                            \
    const float pa_  = rdlane(bE, ((J) + 1) & 63);                \
    const float pb_  = rdlane(bO, ((J) + 1) & 63);                \
    const float qn1_ = rdlane(qd1v, ((J) + 1) & 63);              \
    const float qn2_ = rdlane(qd2v, ((J) + 2) & 63);              \
    const float t_   = fexp2(sQ1 * sig1);                         \
    BAND(J) += fexp2((QE) * sig1);                                \
    const float e2_  = fexp2(sQ2n * sig1);                        \
    const float ns_  = sPP + t_;                                  \
    sigv = (lane == (J)) ? ns_ : sigv;                            \
    sPP  = pa_ + pb_ + e2_;                                       \
    sQ1  = qn1_; sQ2n = qn2_;                                     \
    sig1 = ns_; }

#define CS4(qv, J0) \
    CSTEP(qv.x, J0) CSTEP(qv.y, (J0)+1) CSTEP(qv.z, (J0)+2) CSTEP(qv.w, (J0)+3)

__global__ __launch_bounds__(NT)
void actr_kernel(const float* __restrict__ sp, const float* __restrict__ w,
                 float* __restrict__ out)
{
    __shared__ float  tH[L];
    __shared__ float  acc[L];        // strip + far partial sums
    __shared__ float2 col[L];        // finalized columns {t_j, -decay_j}
    __shared__ float  qT[2][T * T];  // triangle q, j<=l-3 masked, swizzled
    __shared__ float  qd1a[2][T];    // subdiagonal j=l-1
    __shared__ float  qd2a[2][T];    // subdiagonal j=l-2
    __shared__ int    COLF[16];      // col block k published
    __shared__ int    DONE[16];      // contribution counter per row block

    const int bid  = blockIdx.x;
    const int b    = (bid & 7) * 32 + (bid >> 3);   // XCD write-coalescing
    const int tid  = threadIdx.x;
    const int lane = tid & 63;
    const int wv   = tid >> 6;       // 0..7
    const float w0  = w[0];
    const float w1  = w[1];
    const float CSH = w0 / w1;

    for (int i = tid; i < L; i += NT) {
        tH[i]  = sp[i * B + b] * H_CONST;
        acc[i] = 0.0f;
    }
    if (tid < 16) { COLF[tid] = 0; DONE[tid] = 0; }
    __syncthreads();

    // prologue: build qT/qd for blocks 0 and 1 (all 8 waves)
    for (int blk = 0; blk < 2; ++blk) {
        const int base = blk * 64;
        for (int f = tid; f < T * T; f += NT) {
            const int j = f & 63, l2 = f >> 6;
            const float val = -w1 * flog2(tH[base + l2] - tH[base + j]);
            qT[blk][l2 * 64 + (j ^ (4 * (l2 & 15)))] =
                (j <= l2 - 3) ? val : BIGNEG;
            if (j == l2 - 1) qd1a[blk][l2] = val;
            if (j == l2 - 2) qd2a[blk][l2] = val;
        }
    }
    __syncthreads();    // last barrier — none in the main loop

    if (wv == 0) {
        // ================= chain wave =================
        volatile int* vDONE = DONE;
        const int xk = lane & 15;
        for (int k = 0; k < 16; ++k) {
            const int I0 = k * T;
            const int target = (k == 0) ? 0 : (k == 1) ? 7 : k + 13;
            while (vDONE[k] < target) __builtin_amdgcn_s_sleep(2);
            asm volatile("" ::: "memory");

            const float* qb = &qT[k & 1][lane * 64];
            f32x4 q0, q1, q2, q3, q4, q5, q6, q7, q8, q9, qA, qB, qC, qD, qE, qF;
            LOADCH(q0, q1, q2, q3, 0)
            LOADCH(q4, q5, q6, q7, 1)
            LOADCH(q8, q9, qA, qB, 2)
            LOADCH(qC, qD, qE, qF, 3)
            float qd1v  = qd1a[k & 1][lane];
            float qd2v  = qd2a[k & 1][lane];
            float acc_r = acc[I0 + lane];
            KEEP4(q0, q1, q2, q3)
            KEEP4(q4, q5, q6, q7)
            KEEP4(q8, q9, qA, qB)
            KEEP4(qC, qD, qE, qF)
            asm volatile("" : "+v"(qd1v), "+v"(qd2v), "+v"(acc_r));

            // decoupled chain
            float bE   = acc_r + CSH;    // even cols accumulate here (+alpha0)
            float bO   = 0.0f;           // odd cols
            float sig1 = rdlane(bE, 0);  // sigma_0 = alpha0_0
            float sigv = sig1;           // lane 0 correct; others set at their J
            float sPP  = rdlane(bE, 1);  // P_1 = alpha0_1 (no qd2 for row 1)
            float sQ1  = rdlane(qd1v, 1);
            float sQ2n = rdlane(qd2v, 2);
            __builtin_amdgcn_s_setprio(1);
            CS4(q0,  1) CS4(q1,  5) CS4(q2,  9) CS4(q3, 13)
            CS4(q4, 17) CS4(q5, 21) CS4(q6, 25) CS4(q7, 29)
            CS4(q8, 33) CS4(q9, 37) CS4(qA, 41) CS4(qB, 45)
            CS4(qC, 49) CS4(qD, 53) CS4(qE, 57)
            CSTEP(qF.x, 61) CSTEP(qF.y, 62) CSTEP(qF.z, 63)
            __builtin_amdgcn_s_setprio(0);

            const int r = I0 + lane;
            col[r] = make_float2(tH[r], -w1 * sigv);
            asm volatile("" ::: "memory");
            if (lane == 0) atomicExch(&COLF[k], 1);   // release

            if (r > 0) {
                const float act = flog2(sigv - CSH) * LN2;      // ln(s_r)
                const float e   = fexp2((TAU_C - act) * (LOG2E / S_C));
                out[(r - 1) * B + b] = 1.0f / (1.0f + e);
            }
        }
    } else {
        // ================= worker waves =================
        const int p = wv - 1;        // 0..6
        volatile int* vCOLF = COLF;
        for (int c = 0; c < 15; ++c) {
            while (vCOLF[c] == 0) __builtin_amdgcn_s_sleep(2);
            asm volatile("" ::: "memory");

            // --- strip (c+1, c): exact; 16 thr/row ---
            {
                const float2* cb = &col[c * 64];
                #pragma unroll
                for (int m = 0; m < 3; ++m) {
                    const int g = p + 7 * m;          // rowgroup 0..15
                    if (g < 16) {
                        const int rl = 4 * g + (lane >> 4);
                        const int c4 = lane & 15;
                        const float my_t = tH[(c + 1) * 64 + rl];
                        float s = 0.0f;
                        #pragma unroll
                        for (int u = 0; u < 4; ++u) {
                            const float2 cj = cb[c4 + 16 * u];
                            s += fexp2(cj.y * flog2(my_t - cj.x));
                        }
                        s += __shfl_xor(s, 1);
                        s += __shfl_xor(s, 2);
                        s += __shfl_xor(s, 4);
                        s += __shfl_xor(s, 8);
                        if (c4 == 0) atomicAdd(&acc[(c + 1) * 64 + rl], s);
                    }
                }
                asm volatile("" ::: "memory");
                if (lane == 0) atomicAdd(&DONE[c + 1], 1);
            }

            // --- far tiles (r, c) via Chebyshev-8: r = c+2+p, c+9+p ---
            #pragma unroll
            for (int t2 = 0; t2 < 2; ++t2) {
                const int r = c + 2 + p + 7 * t2;
                if (r <= 15) {
                    const int m  = lane >> 3;       // node index
                    const int g  = lane & 7;        // col group
                    const float At  = tH[r * 64];
                    const float Bt  = tH[r * 64 + 63];
                    const float mid = 0.5f * (At + Bt);
                    const float hf  = 0.5f * (Bt - At);
                    const float xm  = fmaf(hf, UNODE[m], mid);
                    const float2* cb = &col[c * 64 + g * 8];
                    float gm = 0.0f;
                    #pragma unroll
                    for (int jj = 0; jj < 8; ++jj) {
                        const float2 cj = cb[jj];
                        gm += fexp2(cj.y * flog2(xm - cj.x));
                    }
                    gm += __shfl_xor(gm, 1);
                    gm += __shfl_xor(gm, 2);
                    gm += __shfl_xor(gm, 4);
                    const float g0 = rdlane(gm,  0), g1 = rdlane(gm,  8);
                    const float g2 = rdlane(gm, 16), g3 = rdlane(gm, 24);
                    const float g4 = rdlane(gm, 32), g5 = rdlane(gm, 40);
                    const float g6 = rdlane(gm, 48), g7 = rdlane(gm, 56);
                    const float s0 = g0 + g7, s1 = g1 + g6;
                    const float s2 = g2 + g5, s3 = g3 + g4;
                    const float d0 = g0 - g7, d1 = g1 - g6;
                    const float d2 = g2 - g5, d3 = g3 - g4;
                    const float a0 = 0.125f * (s0 + s1 + s2 + s3);
                    const float a2 = 0.25f * (CC2 * (s0 - s3) + CC6 * (s1 - s2));
                    const float a4 = 0.25f * CC4 * (s0 - s1 - s2 + s3);
                    const float a6 = 0.25f * (CC6 * (s0 - s3) - CC2 * (s1 - s2));
                    const float a1 = 0.25f * (CC1*d0 + CC3*d1 + CC5*d2 + CC7*d3);
                    const float a3 = 0.25f * (CC3*d0 - CC7*d1 - CC1*d2 - CC5*d3);
                    const float a5 = 0.25f * (CC5*d0 - CC1*d1 + CC7*d2 + CC3*d3);
                    const float a7 = 0.25f * (CC7*d0 - CC5*d1 + CC3*d2 - CC1*d3);
                    const int   i  = r * 64 + lane;
                    const float u  = (tH[i] - mid) * __builtin_amdgcn_rcpf(hf);
                    const float u2 = u + u;
                    float bk1 = a7;
                    float bk  = fmaf(u2, a7, a6);
                    float t3;
                    t3 = fmaf(u2, bk, a5) - bk1; bk1 = bk; bk = t3;
                    t3 = fmaf(u2, bk, a4) - bk1; bk1 = bk; bk = t3;
                    t3 = fmaf(u2, bk, a3) - bk1; bk1 = bk; bk = t3;
                    t3 = fmaf(u2, bk, a2) - bk1; bk1 = bk; bk = t3;
                    t3 = fmaf(u2, bk, a1) - bk1; bk1 = bk; bk = t3;
                    atomicAdd(&acc[i], fmaf(u, bk, a0) - bk1);
                    asm volatile("" ::: "memory");
                    if (lane == 0) atomicAdd(&DONE[r], 1);
                }
            }

            // --- build qT/qd for block c+2 (timestamps only) ---
            if (c <= 13) {
                const int blk  = c + 2;
                const int base = blk * 64;
                float* qn   = &qT[blk & 1][0];
                float* qd1n = qd1a[blk & 1];
                float* qd2n = qd2a[blk & 1];
                const float vt = tH[base + lane];
                #pragma unroll
                for (int m2 = 0; m2 < 10; ++m2) {
                    const int l2 = p + 7 * m2;
                    if (l2 < 64) {
                        const float tl2 = rdlane(vt, l2);
                        const float val = -w1 * flog2(tl2 - vt);
                        qn[l2 * 64 + (lane ^ (4 * (l2 & 15)))] =
                            (lane <= l2 - 3) ? val : BIGNEG;
                        if (lane == l2 - 1) qd1n[l2] = val;
                        if (lane == l2 - 2) qd2n[l2] = val;
                    }
                }
                asm volatile("" ::: "memory");
                if (lane == 0) atomicAdd(&DONE[blk], 1);
            }
        }
    }
}

extern "C" void kernel_launch(void* const* d_in, const int* in_sizes, int n_in,
                              void* d_out, int out_size, void* d_ws, size_t ws_size,
                              hipStream_t stream) {
    const float* sp = (const float*)d_in[0];
    const float* w  = (const float*)d_in[1];
    float* out      = (float*)d_out;
    actr_kernel<<<dim3(B), dim3(NT), 0, stream>>>(sp, w, out);
}

// Round 15
// 53.976 us; speedup vs baseline: 1.3921x; 1.3921x over previous
//
#include <hip/hip_runtime.h>

// ACT-R activation recurrence — async spine + truly-register-resident chain.
// s_i = sum_{j<i} ((t_i-t_j)*H)^(-decay_j),  decay_j = w0 + w1*s_j  (s_0=0)
// (reference's max(diff*H,1) never binds: min gap 0.05 days * 2160 = 108)
// out[i-1,b] = sigmoid((ln(s_i)-TAU)/S), i=1..L-1.
//
// Identity: diff^(-decay_j) = exp2(q_ij*alpha_j), q_ij = -w1*log2(diff_ij),
// alpha = s + w0/w1 > 0; masked q = -1e30 -> term 0.
//
// R15 root cause (from VGPR_Count 44-64 across R9-R14): the compiler SANK the
// LOADCH+KEEP groups into the chain (volatile asms keep only mutual order),
// so ds_read_b128 stalls sat inside the serial loop in every prior round.
// Fix: a single asm GATE with all 16 quads + qd1v as INPUTS and band (chain
// seed) as in/out -> chain start data-depends on every quad; loads can't sink,
// asm outputs can't remat. __launch_bounds__(512,2) gives the 256-VGPR budget.
// Chain step (decoupled): sigma_{j+1} = band[j+1](prefetched) + exp2(qd1*sigma_j)
//   vector band applies col j to lanes >= j+2 (q masks j<=l-2);
//   band[j+2]/qd1[j+2] rdlane-prefetched off the serial path.

constexpr int   L  = 1024;
constexpr int   B  = 256;
constexpr int   T  = 64;
constexpr int   NT = 512;    // 8 waves: 1 chain + 7 workers

constexpr float H_CONST = 86400.0f * 0.025f;   // 2160
constexpr float TAU_C   = -0.704205679427144f;
constexpr float S_C     = 0.254893976981164f;
constexpr float LN2     = 0.69314718055994530942f;
constexpr float LOG2E   = 1.4426950408889634074f;
constexpr float BIGNEG  = -1e30f;

// cos(k*pi/16)
constexpr float CC1 = 0.98078528040323044913f;
constexpr float CC2 = 0.92387953251128675613f;
constexpr float CC3 = 0.83146961230254523708f;
constexpr float CC4 = 0.70710678118654752440f;
constexpr float CC5 = 0.55557023301960222474f;
constexpr float CC6 = 0.38268343236508977173f;
constexpr float CC7 = 0.19509032201612826785f;

__device__ static const float UNODE[8] =
  { CC1, CC3, CC5, CC7, -CC7, -CC5, -CC3, -CC1 };

typedef float f32x4 __attribute__((ext_vector_type(4)));

__device__ __forceinline__ float flog2(float x) { return __builtin_amdgcn_logf(x); }
__device__ __forceinline__ float fexp2(float x) { return __builtin_amdgcn_exp2f(x); }
__device__ __forceinline__ float rdlane(float v, int l) {
    return __uint_as_float(__builtin_amdgcn_readlane(__float_as_uint(v), l));
}

#define LOADCH(p0, p1, p2, p3, c)                                   \
    p0 = *(const f32x4*)(qb + 4 * ((4 * (c) + 0) ^ xk));            \
    p1 = *(const f32x4*)(qb + 4 * ((4 * (c) + 1) ^ xk));            \
    p2 = *(const f32x4*)(qb + 4 * ((4 * (c) + 2) ^ xk));            \
    p3 = *(const f32x4*)(qb + 4 * ((4 * (c) + 3) ^ xk));

// chain step J (0..62): produces sigma_{J+1}.
// entering: sig = sigma_J, sP = band[J+1] (cols<=J-1 + alpha0), sQ = qd1[J+1].
#define CSTEP(QE, J) {                                        \
    const float t_  = fexp2(sQ * sig);      /* chain: mul,exp2 */ \
    const float ns_ = sP + t_;              /* chain: add */      \
    band += fexp2((QE) * sig);              /* band: col J */     \
    const float pn_ = rdlane(band, ((J) + 2) & 63);               \
    const float qn_ = rdlane(qd1v, ((J) + 2) & 63);               \
    sigv = (lane == (J) + 1) ? ns_ : sigv;                        \
    sig = ns_; sP = pn_; sQ = qn_; }

#define CS4(qv, J0) \
    CSTEP(qv.x, J0) CSTEP(qv.y, (J0)+1) CSTEP(qv.z, (J0)+2) CSTEP(qv.w, (J0)+3)

__global__ __launch_bounds__(NT, 2)
void actr_kernel(const float* __restrict__ sp, const float* __restrict__ w,
                 float* __restrict__ out)
{
    __shared__ float  tH[L];
    __shared__ float  acc[L];        // strip + far partial sums
    __shared__ float2 col[L];        // finalized columns {t_j, -decay_j}
    __shared__ float  qT[2][T * T];  // triangle q (j<=l-2), swizzled
    __shared__ float  qd1a[2][T];    // subdiagonal q (j=l-1)
    __shared__ int    COLF[16];      // col block k published
    __shared__ int    DONE[16];      // contribution counter per row block

    const int bid  = blockIdx.x;
    const int b    = (bid & 7) * 32 + (bid >> 3);   // XCD write-coalescing
    const int tid  = threadIdx.x;
    const int lane = tid & 63;
    const int wv   = tid >> 6;       // 0..7
    const float w0  = w[0];
    const float w1  = w[1];
    const float CSH = w0 / w1;

    for (int i = tid; i < L; i += NT) {
        tH[i]  = sp[i * B + b] * H_CONST;
        acc[i] = 0.0f;
    }
    if (tid < 16) { COLF[tid] = 0; DONE[tid] = 0; }
    __syncthreads();

    // prologue: build qT/qd1 for blocks 0 and 1 (all 8 waves)
    for (int blk = 0; blk < 2; ++blk) {
        const int base = blk * 64;
        for (int f = tid; f < T * T; f += NT) {
            const int j = f & 63, l2 = f >> 6;
            const float val = -w1 * flog2(tH[base + l2] - tH[base + j]);
            qT[blk][l2 * 64 + (j ^ (4 * (l2 & 15)))] =
                (j <= l2 - 2) ? val : BIGNEG;
            if (j == l2 - 1) qd1a[blk][l2] = val;
        }
    }
    __syncthreads();    // last barrier — none in the main loop

    if (wv == 0) {
        // ================= chain wave =================
        volatile int* vDONE = DONE;
        const int xk = lane & 15;
        for (int k = 0; k < 16; ++k) {
            const int I0 = k * T;
            const int target = (k == 0) ? 0 : (k == 1) ? 7 : k + 13;
            while (vDONE[k] < target) __builtin_amdgcn_s_sleep(2);
            asm volatile("" ::: "memory");

            const float* qb = &qT[k & 1][lane * 64];
            f32x4 q0, q1, q2, q3, q4, q5, q6, q7, q8, q9, qA, qB, qC, qD, qE, qF;
            LOADCH(q0, q1, q2, q3, 0)
            LOADCH(q4, q5, q6, q7, 1)
            LOADCH(q8, q9, qA, qB, 2)
            LOADCH(qC, qD, qE, qF, 3)
            float qd1v = qd1a[k & 1][lane];
            float band = acc[I0 + lane] + CSH;   // alpha0 seed + cols as applied

            // GATE: chain seed depends on ALL quads + qd1v -> loads cannot
            // sink into the chain; asm results cannot be rematerialized.
            asm volatile("" : "+v"(band)
                         : "v"(q0), "v"(q1), "v"(q2), "v"(q3),
                           "v"(q4), "v"(q5), "v"(q6), "v"(q7),
                           "v"(q8), "v"(q9), "v"(qA), "v"(qB),
                           "v"(qC), "v"(qD), "v"(qE), "v"(qF), "v"(qd1v));

            float sig  = rdlane(band, 0);        // sigma_0
            float sP   = rdlane(band, 1);        // alpha0_1
            float sQ   = rdlane(qd1v, 1);
            float sigv = sig;                    // lane 0's final value
            __builtin_amdgcn_s_setprio(1);
            CS4(q0,  0) CS4(q1,  4) CS4(q2,  8) CS4(q3, 12)
            CS4(q4, 16) CS4(q5, 20) CS4(q6, 24) CS4(q7, 28)
            CS4(q8, 32) CS4(q9, 36) CS4(qA, 40) CS4(qB, 44)
            CS4(qC, 48) CS4(qD, 52) CS4(qE, 56)
            CSTEP(qF.x, 60) CSTEP(qF.y, 61) CSTEP(qF.z, 62)
            __builtin_amdgcn_s_setprio(0);

            const int r = I0 + lane;
            col[r] = make_float2(tH[r], -w1 * sigv);
            asm volatile("" ::: "memory");
            if (lane == 0) atomicExch(&COLF[k], 1);   // release

            if (r > 0) {
                const float act = flog2(sigv - CSH) * LN2;      // ln(s_r)
                const float e   = fexp2((TAU_C - act) * (LOG2E / S_C));
                out[(r - 1) * B + b] = 1.0f / (1.0f + e);
            }
        }
    } else {
        // ================= worker waves =================
        const int p = wv - 1;        // 0..6
        volatile int* vCOLF = COLF;
        for (int c = 0; c < 15; ++c) {
            while (vCOLF[c] == 0) __builtin_amdgcn_s_sleep(2);
            asm volatile("" ::: "memory");

            // --- strip (c+1, c): exact; 16 thr/row ---
            {
                const float2* cb = &col[c * 64];
                #pragma unroll
                for (int m = 0; m < 3; ++m) {
                    const int g = p + 7 * m;          // rowgroup 0..15
                    if (g < 16) {
                        const int rl = 4 * g + (lane >> 4);
                        const int c4 = lane & 15;
                        const float my_t = tH[(c + 1) * 64 + rl];
                        float s = 0.0f;
                        #pragma unroll
                        for (int u = 0; u < 4; ++u) {
                            const float2 cj = cb[c4 + 16 * u];
                            s += fexp2(cj.y * flog2(my_t - cj.x));
                        }
                        s += __shfl_xor(s, 1);
                        s += __shfl_xor(s, 2);
                        s += __shfl_xor(s, 4);
                        s += __shfl_xor(s, 8);
                        if (c4 == 0) atomicAdd(&acc[(c + 1) * 64 + rl], s);
                    }
                }
                asm volatile("" ::: "memory");
                if (lane == 0) atomicAdd(&DONE[c + 1], 1);
            }

            // --- far tiles (r, c) via Chebyshev-8: r = c+2+p, c+9+p ---
            #pragma unroll
            for (int t2 = 0; t2 < 2; ++t2) {
                const int r = c + 2 + p + 7 * t2;
                if (r <= 15) {
                    const int m  = lane >> 3;       // node index
                    const int g  = lane & 7;        // col group
                    const float At  = tH[r * 64];
                    const float Bt  = tH[r * 64 + 63];
                    const float mid = 0.5f * (At + Bt);
                    const float hf  = 0.5f * (Bt - At);
                    const float xm  = fmaf(hf, UNODE[m], mid);
                    const float2* cb = &col[c * 64 + g * 8];
                    float gm = 0.0f;
                    #pragma unroll
                    for (int jj = 0; jj < 8; ++jj) {
                        const float2 cj = cb[jj];
                        gm += fexp2(cj.y * flog2(xm - cj.x));
                    }
                    gm += __shfl_xor(gm, 1);
                    gm += __shfl_xor(gm, 2);
                    gm += __shfl_xor(gm, 4);
                    const float g0 = rdlane(gm,  0), g1 = rdlane(gm,  8);
                    const float g2 = rdlane(gm, 16), g3 = rdlane(gm, 24);
                    const float g4 = rdlane(gm, 32), g5 = rdlane(gm, 40);
                    const float g6 = rdlane(gm, 48), g7 = rdlane(gm, 56);
                    const float s0 = g0 + g7, s1 = g1 + g6;
                    const float s2 = g2 + g5, s3 = g3 + g4;
                    const float d0 = g0 - g7, d1 = g1 - g6;
                    const float d2 = g2 - g5, d3 = g3 - g4;
                    const float a0 = 0.125f * (s0 + s1 + s2 + s3);
                    const float a2 = 0.25f * (CC2 * (s0 - s3) + CC6 * (s1 - s2));
                    const float a4 = 0.25f * CC4 * (s0 - s1 - s2 + s3);
                    const float a6 = 0.25f * (CC6 * (s0 - s3) - CC2 * (s1 - s2));
                    const float a1 = 0.25f * (CC1*d0 + CC3*d1 + CC5*d2 + CC7*d3);
                    const float a3 = 0.25f * (CC3*d0 - CC7*d1 - CC1*d2 - CC5*d3);
                    const float a5 = 0.25f * (CC5*d0 - CC1*d1 + CC7*d2 + CC3*d3);
                    const float a7 = 0.25f * (CC7*d0 - CC5*d1 + CC3*d2 - CC1*d3);
                    const int   i  = r * 64 + lane;
                    const float u  = (tH[i] - mid) * __builtin_amdgcn_rcpf(hf);
                    const float u2 = u + u;
                    float bk1 = a7;
                    float bk  = fmaf(u2, a7, a6);
                    float t3;
                    t3 = fmaf(u2, bk, a5) - bk1; bk1 = bk; bk = t3;
                    t3 = fmaf(u2, bk, a4) - bk1; bk1 = bk; bk = t3;
                    t3 = fmaf(u2, bk, a3) - bk1; bk1 = bk; bk = t3;
                    t3 = fmaf(u2, bk, a2) - bk1; bk1 = bk; bk = t3;
                    t3 = fmaf(u2, bk, a1) - bk1; bk1 = bk; bk = t3;
                    atomicAdd(&acc[i], fmaf(u, bk, a0) - bk1);
                    asm volatile("" ::: "memory");
                    if (lane == 0) atomicAdd(&DONE[r], 1);
                }
            }

            // --- build qT/qd1 for block c+2 (timestamps only) ---
            if (c <= 13) {
                const int blk  = c + 2;
                const int base = blk * 64;
                float* qn   = &qT[blk & 1][0];
                float* qd1n = qd1a[blk & 1];
                const float vt = tH[base + lane];
                #pragma unroll
                for (int m2 = 0; m2 < 10; ++m2) {
                    const int l2 = p + 7 * m2;
                    if (l2 < 64) {
                        const float tl2 = rdlane(vt, l2);
                        const float val = -w1 * flog2(tl2 - vt);
                        qn[l2 * 64 + (lane ^ (4 * (l2 & 15)))] =
                            (lane <= l2 - 2) ? val : BIGNEG;
                        if (lane == l2 - 1) qd1n[l2] = val;
                    }
                }
                asm volatile("" ::: "memory");
                if (lane == 0) atomicAdd(&DONE[blk], 1);
            }
        }
    }
}

extern "C" void kernel_launch(void* const* d_in, const int* in_sizes, int n_in,
                              void* d_out, int out_size, void* d_ws, size_t ws_size,
                              hipStream_t stream) {
    const float* sp = (const float*)d_in[0];
    const float* w  = (const float*)d_in[1];
    float* out      = (float*)d_out;
    actr_kernel<<<dim3(B), dim3(NT), 0, stream>>>(sp, w, out);
}

// Round 16
// 45.793 us; speedup vs baseline: 1.6409x; 1.1787x over previous
//
#include <hip/hip_runtime.h>

// ACT-R activation recurrence — async spine, chain-folded strip, isolated SIMD0.
// s_i = sum_{j<i} ((t_i-t_j)*H)^(-decay_j),  decay_j = w0 + w1*s_j  (s_0=0)
// (reference's max(diff*H,1) never binds: min gap 0.05 days * 2160 = 108)
// out[i-1,b] = sigmoid((ln(s_i)-TAU)/S), i=1..L-1.
//
// Identity: diff^(-decay_j) = exp2(q_ij*alpha_j), q_ij = -w1*log2(diff_ij),
// alpha = s + w0/w1 > 0; masked q = -1e30 -> term 0.
//
// R16: evidence (R13 6instr/link=47us, R15 9=54, R14 12=75) says the chain is
// ISSUE-bound: wave0 shares SIMD0 with worker wave4 (async spine: workers run
// concurrently). Fix 1: wave4 is idle -> SIMD0 = chain alone (workers have
// ~6x slack). Fix 2: strip folded into the chain: during block k's 64 steps,
// beta += exp2(qS_j * sigma_j) accumulates the strip into block k+1
// (qS = 64x64 timestamp tile, built by workers a phase early) -> removes the
// worker strip AND one handoff per phase; chain flows k -> k+1 directly.
// Workers (waves 1-3,5-7): Chebyshev far tiles (r,c) + build qT[c+2]/qS[c+3].

constexpr int   L  = 1024;
constexpr int   B  = 256;
constexpr int   T  = 64;
constexpr int   NT = 512;    // 8 waves: wave0 chain, wave4 idle, 6 workers

constexpr float H_CONST = 86400.0f * 0.025f;   // 2160
constexpr float TAU_C   = -0.704205679427144f;
constexpr float S_C     = 0.254893976981164f;
constexpr float LN2     = 0.69314718055994530942f;
constexpr float LOG2E   = 1.4426950408889634074f;
constexpr float BIGNEG  = -1e30f;

// cos(k*pi/16)
constexpr float CC1 = 0.98078528040323044913f;
constexpr float CC2 = 0.92387953251128675613f;
constexpr float CC3 = 0.83146961230254523708f;
constexpr float CC4 = 0.70710678118654752440f;
constexpr float CC5 = 0.55557023301960222474f;
constexpr float CC6 = 0.38268343236508977173f;
constexpr float CC7 = 0.19509032201612826785f;

__device__ static const float UNODE[8] =
  { CC1, CC3, CC5, CC7, -CC7, -CC5, -CC3, -CC1 };

typedef float f32x4 __attribute__((ext_vector_type(4)));

__device__ __forceinline__ float flog2(float x) { return __builtin_amdgcn_logf(x); }
__device__ __forceinline__ float fexp2(float x) { return __builtin_amdgcn_exp2f(x); }
__device__ __forceinline__ float rdlane(float v, int l) {
    return __uint_as_float(__builtin_amdgcn_readlane(__float_as_uint(v), l));
}

#define LOADQ(p0, p1, p2, p3, QB, c)                                \
    p0 = *(const f32x4*)((QB) + 4 * ((4 * (c) + 0) ^ xk));          \
    p1 = *(const f32x4*)((QB) + 4 * ((4 * (c) + 1) ^ xk));          \
    p2 = *(const f32x4*)((QB) + 4 * ((4 * (c) + 2) ^ xk));          \
    p3 = *(const f32x4*)((QB) + 4 * ((4 * (c) + 3) ^ xk));

// one chain step: sigma_J broadcast; band (alpha, this block) + strip (beta,
// next block) updates. Lane l's alpha is final after step l (qT masks j>=l).
#define CST(TE, SE, J) {                         \
    const float sg = rdlane(alpha, J);           \
    alpha += fexp2((TE) * sg);                   \
    beta  += fexp2((SE) * sg); }

#define CST4(tv, sv, J) \
    CST(tv.x, sv.x, J) CST(tv.y, sv.y, (J)+1) \
    CST(tv.z, sv.z, (J)+2) CST(tv.w, sv.w, (J)+3)

__global__ __launch_bounds__(NT)
void actr_kernel(const float* __restrict__ sp, const float* __restrict__ w,
                 float* __restrict__ out)
{
    __shared__ float  tH[L];
    __shared__ float  acc[L];        // far-field partial sums
    __shared__ float2 col[L];        // finalized columns {t_j, -decay_j}
    __shared__ float  qT[2][T * T];  // triangle q (j<l), swizzled
    __shared__ float  qS[2][T * T];  // strip tile S_b: rows blk b, cols blk b-1
    __shared__ int    COLF[16];
    __shared__ int    DONE[16];

    const int bid  = blockIdx.x;
    const int b    = (bid & 7) * 32 + (bid >> 3);   // XCD write-coalescing
    const int tid  = threadIdx.x;
    const int lane = tid & 63;
    const int wv   = tid >> 6;       // 0..7
    const float w0  = w[0];
    const float w1  = w[1];
    const float CSH = w0 / w1;

    for (int i = tid; i < L; i += NT) {
        tH[i]  = sp[i * B + b] * H_CONST;
        acc[i] = 0.0f;
    }
    if (tid < 16) { COLF[tid] = 0; DONE[tid] = 0; }
    __syncthreads();

    // prologue (all 8 waves): qT blocks 0,1; qS blocks 1,2
    for (int blk = 0; blk < 2; ++blk) {
        const int base = blk * 64;
        for (int f = tid; f < T * T; f += NT) {
            const int j = f & 63, l2 = f >> 6;
            const float val = -w1 * flog2(tH[base + l2] - tH[base + j]);
            qT[blk][l2 * 64 + (j ^ (4 * (l2 & 15)))] = (j < l2) ? val : BIGNEG;
        }
    }
    for (int sb = 1; sb <= 2; ++sb) {
        const int br = sb * 64, bc = (sb - 1) * 64;
        for (int f = tid; f < T * T; f += NT) {
            const int j = f & 63, i2 = f >> 6;
            qS[sb & 1][i2 * 64 + (j ^ (4 * (i2 & 15)))] =
                -w1 * flog2(tH[br + i2] - tH[bc + j]);
        }
    }
    __syncthreads();    // last barrier

    if (wv == 0) {
        // ================= chain wave (SIMD0, alone) =================
        volatile int* vDONE = DONE;
        const int xk = lane & 15;
        float beta = 0.0f;           // strip into the NEXT block
        for (int k = 0; k < 16; ++k) {
            const int I0 = k * T;
            const int target = (k <= 1) ? 0 : k + 5;   // (k-1) far + 6 build
            while (vDONE[k] < target) __builtin_amdgcn_s_sleep(2);
            asm volatile("" ::: "memory");

            const float* qbT = &qT[k & 1][lane * 64];
            const float* qbS = &qS[(k + 1) & 1][lane * 64];
            f32x4 t0, t1, t2, t3, t4, t5, t6, t7, t8, t9, tA, tB, tC, tD, tE, tF;
            f32x4 s0, s1, s2, s3, s4, s5, s6, s7, s8, s9, sA, sB, sC, sD, sE, sF;
            LOADQ(t0, t1, t2, t3, qbT, 0)
            LOADQ(s0, s1, s2, s3, qbS, 0)
            LOADQ(t4, t5, t6, t7, qbT, 1)
            LOADQ(s4, s5, s6, s7, qbS, 1)
            LOADQ(t8, t9, tA, tB, qbT, 2)
            LOADQ(s8, s9, sA, sB, qbS, 2)
            LOADQ(tC, tD, tE, tF, qbT, 3)
            LOADQ(sC, sD, sE, sF, qbS, 3)

            float alpha = acc[I0 + lane] + beta + CSH;
            beta = 0.0f;
            __builtin_amdgcn_s_setprio(1);
            CST4(t0, s0,  0) CST4(t1, s1,  4) CST4(t2, s2,  8) CST4(t3, s3, 12)
            CST4(t4, s4, 16) CST4(t5, s5, 20) CST4(t6, s6, 24) CST4(t7, s7, 28)
            CST4(t8, s8, 32) CST4(t9, s9, 36) CST4(tA, sA, 40) CST4(tB, sB, 44)
            CST4(tC, sC, 48) CST4(tD, sD, 52) CST4(tE, sE, 56) CST4(tF, sF, 60)
            __builtin_amdgcn_s_setprio(0);

            const int r = I0 + lane;
            col[r] = make_float2(tH[r], -w1 * alpha);   // alpha lane l = sigma_l
            asm volatile("" ::: "memory");
            if (lane == 0) atomicExch(&COLF[k], 1);     // release

            if (r > 0) {
                const float act = flog2(alpha - CSH) * LN2;     // ln(s_r)
                const float e   = fexp2((TAU_C - act) * (LOG2E / S_C));
                out[(r - 1) * B + b] = 1.0f / (1.0f + e);
            }
        }
    } else if (wv != 4) {
        // ================= 6 worker waves (never on SIMD0) =================
        const int p = (wv < 4) ? (wv - 1) : (wv - 2);   // 0..5
        volatile int* vCOLF = COLF;
        for (int c = 0; c < 14; ++c) {
            while (vCOLF[c] == 0) __builtin_amdgcn_s_sleep(2);
            asm volatile("" ::: "memory");

            // --- far tiles (r, c) via Chebyshev-8: r = c+2+p+6m ---
            #pragma unroll
            for (int t2 = 0; t2 < 3; ++t2) {
                const int r = c + 2 + p + 6 * t2;
                if (r <= 15) {
                    const int m  = lane >> 3;
                    const int g  = lane & 7;
                    const float At  = tH[r * 64];
                    const float Bt  = tH[r * 64 + 63];
                    const float mid = 0.5f * (At + Bt);
                    const float hf  = 0.5f * (Bt - At);
                    const float xm  = fmaf(hf, UNODE[m], mid);
                    const float2* cb = &col[c * 64 + g * 8];
                    float gm = 0.0f;
                    #pragma unroll
                    for (int jj = 0; jj < 8; ++jj) {
                        const float2 cj = cb[jj];
                        gm += fexp2(cj.y * flog2(xm - cj.x));
                    }
                    gm += __shfl_xor(gm, 1);
                    gm += __shfl_xor(gm, 2);
                    gm += __shfl_xor(gm, 4);
                    const float g0 = rdlane(gm,  0), g1 = rdlane(gm,  8);
                    const float g2 = rdlane(gm, 16), g3 = rdlane(gm, 24);
                    const float g4 = rdlane(gm, 32), g5 = rdlane(gm, 40);
                    const float g6 = rdlane(gm, 48), g7 = rdlane(gm, 56);
                    const float s0 = g0 + g7, s1 = g1 + g6;
                    const float s2 = g2 + g5, s3 = g3 + g4;
                    const float d0 = g0 - g7, d1 = g1 - g6;
                    const float d2 = g2 - g5, d3 = g3 - g4;
                    const float a0 = 0.125f * (s0 + s1 + s2 + s3);
                    const float a2 = 0.25f * (CC2 * (s0 - s3) + CC6 * (s1 - s2));
                    const float a4 = 0.25f * CC4 * (s0 - s1 - s2 + s3);
                    const float a6 = 0.25f * (CC6 * (s0 - s3) - CC2 * (s1 - s2));
                    const float a1 = 0.25f * (CC1*d0 + CC3*d1 + CC5*d2 + CC7*d3);
                    const float a3 = 0.25f * (CC3*d0 - CC7*d1 - CC1*d2 - CC5*d3);
                    const float a5 = 0.25f * (CC5*d0 - CC1*d1 + CC7*d2 + CC3*d3);
                    const float a7 = 0.25f * (CC7*d0 - CC5*d1 + CC3*d2 - CC1*d3);
                    const int   i  = r * 64 + lane;
                    const float u  = (tH[i] - mid) * __builtin_amdgcn_rcpf(hf);
                    const float u2 = u + u;
                    float bk1 = a7;
                    float bk  = fmaf(u2, a7, a6);
                    float t3;
                    t3 = fmaf(u2, bk, a5) - bk1; bk1 = bk; bk = t3;
                    t3 = fmaf(u2, bk, a4) - bk1; bk1 = bk; bk = t3;
                    t3 = fmaf(u2, bk, a3) - bk1; bk1 = bk; bk = t3;
                    t3 = fmaf(u2, bk, a2) - bk1; bk1 = bk; bk = t3;
                    t3 = fmaf(u2, bk, a1) - bk1; bk1 = bk; bk = t3;
                    atomicAdd(&acc[i], fmaf(u, bk, a0) - bk1);
                    asm volatile("" ::: "memory");
                    if (lane == 0) atomicAdd(&DONE[r], 1);
                }
            }

            // --- build qT[c+2] and qS[c+3] (timestamps only) ---
            {
                const int blk  = c + 2;
                const float vtB = tH[blk * 64 + lane];          // block c+2
                float* qnT = &qT[blk & 1][0];
                #pragma unroll
                for (int m2 = 0; m2 < 11; ++m2) {
                    const int l2 = p + 6 * m2;
                    if (l2 < 64) {
                        const float tl2 = rdlane(vtB, l2);
                        const float val = -w1 * flog2(tl2 - vtB);
                        qnT[l2 * 64 + (lane ^ (4 * (l2 & 15)))] =
                            (lane < l2) ? val : BIGNEG;
                    }
                }
                if (c <= 12) {      // S_{c+3}: rows block c+3, cols block c+2
                    const float vtC = tH[(c + 3) * 64 + lane];
                    float* qnS = &qS[(c + 3) & 1][0];
                    #pragma unroll
                    for (int m2 = 0; m2 < 11; ++m2) {
                        const int i2 = p + 6 * m2;
                        if (i2 < 64) {
                            const float tri = rdlane(vtC, i2);
                            qnS[i2 * 64 + (lane ^ (4 * (i2 & 15)))] =
                                -w1 * flog2(tri - vtB);
                        }
                    }
                }
                asm volatile("" ::: "memory");
                if (lane == 0) atomicAdd(&DONE[blk], 1);
            }
        }
    }
    // wave 4: idle — SIMD0 belongs to the chain
}

extern "C" void kernel_launch(void* const* d_in, const int* in_sizes, int n_in,
                              void* d_out, int out_size, void* d_ws, size_t ws_size,
                              hipStream_t stream) {
    const float* sp = (const float*)d_in[0];
    const float* w  = (const float*)d_in[1];
    float* out      = (float*)d_out;
    actr_kernel<<<dim3(B), dim3(NT), 0, stream>>>(sp, w, out);
}